// Round 11
// baseline (196.109 us; speedup 1.0000x reference)
//
#include <hip/hip_runtime.h>

#define BB 64
#define CC 512
#define NPIX 784
#define KK 32
#define NSA 13          // kA: 13 splits of 64 px (split 12 overlaps: p0=720)
#define AS 800          // A row stride in shorts (784 padded to 25*32)
#define XS_S 66         // kA LDS x-tile row stride (shorts): conflict-free reads/writes
#define NSTEP 24        // kB full 32-wide n-steps (24*32 = 768), +1 predicated tail

typedef __attribute__((ext_vector_type(8))) short short8;
typedef __attribute__((ext_vector_type(4))) float floatx4;
typedef __attribute__((ext_vector_type(4))) unsigned short ushort4v;

// workspace (in shorts from Ag): A bf16 [64][32][800], wsum_p f32 [13][64][32],
// cw bf16 [32][512], csq f32 [32]
#define WSUM_OFF (BB * KK * AS)                   // 1,638,400 shorts
#define CWB_OFF  (WSUM_OFF + 2 * NSA * BB * KK)   // +53,248 -> 1,691,648 (16B-aligned)
#define CSQ_OFF  (CWB_OFF + KK * CC)              // +16,384 -> 1,708,032 (16B-aligned)

__device__ __forceinline__ unsigned short f2bf(float f) {
    union { float f; unsigned u; } v; v.f = f;
    return (unsigned short)((v.u + 0x7FFFu + ((v.u >> 16) & 1u)) >> 16);
}
__device__ __forceinline__ short8 pack8(const float4& a, const float4& b) {
    short8 r;
    r[0] = (short)f2bf(a.x); r[1] = (short)f2bf(a.y);
    r[2] = (short)f2bf(a.z); r[3] = (short)f2bf(a.w);
    r[4] = (short)f2bf(b.x); r[5] = (short)f2bf(b.y);
    r[6] = (short)f2bf(b.z); r[7] = (short)f2bf(b.w);
    return r;
}

// ---------------------------------------------------------------------------
// kPrep: pack cw -> bf16 [32][512] + csq[32] into workspace (runs once, 1 block)
// ---------------------------------------------------------------------------
__global__ __launch_bounds__(256) void kPrep(const float* __restrict__ cw,
                                             unsigned short* __restrict__ Ag)
{
    __shared__ float red[KK][8];
    const int t = threadIdx.x;
    const int k = t >> 3, part = t & 7;
    unsigned short* cwb = Ag + CWB_OFF;
    float* csqg = (float*)(Ag + CSQ_OFF);
    const float* cp = cw + k * CC + part * 64;
    float s = 0.f;
#pragma unroll 16
    for (int i = 0; i < 64; ++i) {
        const float v = cp[i];
        s += v * v;
        cwb[k * CC + part * 64 + i] = f2bf(v);
    }
    red[k][part] = s;
    __syncthreads();
    if (t < KK) {
        float ss = 0.f;
#pragma unroll
        for (int p = 0; p < 8; ++p) ss += red[t][p];
        csqg[t] = ss;
    }
}

// ---------------------------------------------------------------------------
// kA: per (64-px split, batch): A[k][px] = softmax_k(scale_k*(xsq+csq_k-2 x.c_k))
//  - DENSE staging: whole x-tile [512c][64px] -> bf16 LDS (stride 66) in one
//    bulk pass of coalesced float4 loads (1KB/instr, kB-proven ~4.7TB/s
//    pattern), 4 explicit groups of 8 loads -> >=8KB/wave in flight.
//    ONE barrier total (not per chunk -- the r4/r7/r9 killer).
//  - xsq computed fp32 during staging (removes xsq+shfl from inner loop).
//  - compute: barrier-free; a-frag = 8x ds_read_u16 (conflict-free: quads on
//    disjoint bank octets, col-pairs share dwords -> broadcast).
//  - cw b-frags: direct global short8 from kPrep's packed bf16 (L1/L2-hot).
// ---------------------------------------------------------------------------
__global__ __launch_bounds__(256, 2) void kA(const float* __restrict__ x,
                                             const float* __restrict__ scale,
                                             unsigned short* __restrict__ Ag)
{
    __shared__ __align__(16) unsigned short xs[CC * XS_S];   // 67584 B
    __shared__ float xsq_p[16][64];
    __shared__ float xsq_l[64];
    __shared__ float wredA[4][KK];

    const int t    = threadIdx.x;
    const int lane = t & 63, w = t >> 6;
    const int col  = lane & 15, quad = lane >> 4;
    const int split = blockIdx.x, b = blockIdx.y;
    const int p0    = (split < 12) ? split * 64 : 720;   // split 12 overlaps by 48 px

    // ---- zero A pad region n in [784,800) once per batch (idempotent) ----
    if (split == 0 && t < 64) {
        const short8 z = {0, 0, 0, 0, 0, 0, 0, 0};
        const int k = t >> 1, off = (t & 1) * 8;
        *(short8*)&Ag[(size_t)b * KK * AS + (size_t)k * AS + NPIX + off] = z;
    }

    // ---- bulk staging: 32 coalesced float4 loads/thread, 4 groups of 8 ----
    const float* xb = x + (size_t)b * CC * NPIX + p0;
    const int csub = t >> 4;          // c-sub 0..15
    const int pg   = t & 15;          // px float4-group
    float sx0 = 0.f, sx1 = 0.f, sx2 = 0.f, sx3 = 0.f;
#pragma unroll
    for (int g = 0; g < 4; ++g) {
        float4 v[8];
#pragma unroll
        for (int i = 0; i < 8; ++i) {
            const int c = (g * 8 + i) * 16 + csub;
            v[i] = *(const float4*)&xb[(size_t)c * NPIX + pg * 4];
        }
#pragma unroll
        for (int i = 0; i < 8; ++i) {
            const int c = (g * 8 + i) * 16 + csub;
            sx0 += v[i].x * v[i].x; sx1 += v[i].y * v[i].y;
            sx2 += v[i].z * v[i].z; sx3 += v[i].w * v[i].w;
            ushort4v p; p.x = f2bf(v[i].x); p.y = f2bf(v[i].y);
            p.z = f2bf(v[i].z); p.w = f2bf(v[i].w);
            *(ushort4v*)&xs[c * XS_S + pg * 4] = p;
        }
    }
    xsq_p[csub][pg * 4 + 0] = sx0;
    xsq_p[csub][pg * 4 + 1] = sx1;
    xsq_p[csub][pg * 4 + 2] = sx2;
    xsq_p[csub][pg * 4 + 3] = sx3;
    __syncthreads();
    if (t < 64) {
        float s = 0.f;
#pragma unroll
        for (int r = 0; r < 16; ++r) s += xsq_p[r][t];
        xsq_l[t] = s;
    }
    __syncthreads();

    // ---- compute: 16 kc-steps, barrier-free ----
    const unsigned short* cwb = Ag + CWB_OFF;
    const float* csqg = (const float*)(Ag + CSQ_OFF);
    const float s0 = scale[col], s1 = scale[col + 16];
    const float q0 = csqg[col], q1 = csqg[col + 16];
    const int wpx = w * 16 + col;

    floatx4 acc0 = {0.f, 0.f, 0.f, 0.f};
    floatx4 acc1 = {0.f, 0.f, 0.f, 0.f};
#pragma unroll
    for (int kc = 0; kc < 16; ++kc) {
        const int cb = kc * 32 + quad * 8;
        short8 a;
#pragma unroll
        for (int j = 0; j < 8; ++j) a[j] = (short)xs[(cb + j) * XS_S + wpx];
        const short8 b0 = *(const short8*)&cwb[col * CC + cb];
        const short8 b1 = *(const short8*)&cwb[(col + 16) * CC + cb];
        acc0 = __builtin_amdgcn_mfma_f32_16x16x32_bf16(a, b0, acc0, 0, 0, 0);
        acc1 = __builtin_amdgcn_mfma_f32_16x16x32_bf16(a, b1, acc1, 0, 0, 0);
    }

    // fused softmax epilogue; D row = px = quad*4+r, col = k
    unsigned short* Ab = Ag + (size_t)b * KK * AS + p0 + w * 16;
    float ts0 = 0.f, ts1 = 0.f;   // per-lane partial wsum over this tile
#pragma unroll
    for (int r = 0; r < 4; ++r) {
        const float xq = xsq_l[w * 16 + quad * 4 + r];
        const float d0 = s0 * (xq + q0 - 2.f * acc0[r]);
        const float d1 = s1 * (xq + q1 - 2.f * acc1[r]);
        float mx = fmaxf(d0, d1);
        mx = fmaxf(mx, __shfl_xor(mx, 1));
        mx = fmaxf(mx, __shfl_xor(mx, 2));
        mx = fmaxf(mx, __shfl_xor(mx, 4));
        mx = fmaxf(mx, __shfl_xor(mx, 8));
        const float e0 = __expf(d0 - mx), e1 = __expf(d1 - mx);
        float sm = e0 + e1;
        sm += __shfl_xor(sm, 1);
        sm += __shfl_xor(sm, 2);
        sm += __shfl_xor(sm, 4);
        sm += __shfl_xor(sm, 8);
        const float inv = 1.f / sm;
        const float a0 = e0 * inv, a1 = e1 * inv;
        Ab[col * AS + quad * 4 + r]        = f2bf(a0);
        Ab[(col + 16) * AS + quad * 4 + r] = f2bf(a1);
        ts0 += a0; ts1 += a1;
    }

    // per-tile wsum: reduce over the 4 quads (16 px of this tile)
    ts0 += __shfl_xor(ts0, 16); ts0 += __shfl_xor(ts0, 32);
    ts1 += __shfl_xor(ts1, 16); ts1 += __shfl_xor(ts1, 32);
    if (quad == 0) { wredA[w][col] = ts0; wredA[w][col + 16] = ts1; }
    __syncthreads();
    if (t < KK) {
        // split 12: tiles w=0..2 duplicate split 11's coverage -> count only w=3
        float s;
        if (split < 12) s = wredA[0][t] + wredA[1][t] + wredA[2][t] + wredA[3][t];
        else            s = wredA[3][t];
        float* wsf = (float*)(Ag + WSUM_OFF);
        wsf[(size_t)(split * BB + b) * KK + t] = s;
    }
}

// ---------------------------------------------------------------------------
// kB: per (c-chunk of 64, batch): out[k][c] = sum_n A[k][n] x[c][n] - wsum_k cw[k][c]
//  - barrier-free main loop, A (L2-hot) and x (L3-hot from kA) direct from global
//  - wsum from kA's per-split partials (13 adds per k)
// ---------------------------------------------------------------------------
__global__ __launch_bounds__(256) void kB(const float* __restrict__ x,
                                          const float* __restrict__ cw,
                                          const unsigned short* __restrict__ Ag,
                                          float* __restrict__ out)
{
    __shared__ float wsum_l[KK];

    const int t    = threadIdx.x;
    const int lane = t & 63, w = t >> 6;
    const int col  = lane & 15, quad = lane >> 4;
    const int cch  = blockIdx.x, b = blockIdx.y;

    const unsigned short* Ab = Ag + (size_t)b * KK * AS;

    // ---- wsum: sum kA's 13 per-split partials ----
    if (t < KK) {
        const float* wsf = (const float*)(Ag + WSUM_OFF);
        float s = 0.f;
#pragma unroll
        for (int sp = 0; sp < NSA; ++sp) s += wsf[(size_t)(sp * BB + b) * KK + t];
        wsum_l[t] = s;
    }

    // ---- main GEMM: this wave owns 16 c-rows; contract n = 0..800 ----
    const int c = cch * 64 + w * 16 + col;
    const float* xp = x + ((size_t)b * CC + c) * NPIX;
    const unsigned short* a0p = Ab + (size_t)col * AS;
    const unsigned short* a1p = Ab + (size_t)(col + 16) * AS;
    const int qo = quad * 8;

    floatx4 acc0 = {0.f, 0.f, 0.f, 0.f};
    floatx4 acc1 = {0.f, 0.f, 0.f, 0.f};
#pragma unroll 6
    for (int s = 0; s < NSTEP; ++s) {
        const int off = s * 32 + qo;
        const short8 av0 = *(const short8*)&a0p[off];
        const short8 av1 = *(const short8*)&a1p[off];
        const float4 xv0 = *(const float4*)&xp[off];
        const float4 xv1 = *(const float4*)&xp[off + 4];
        const short8 bv = pack8(xv0, xv1);
        acc0 = __builtin_amdgcn_mfma_f32_16x16x32_bf16(av0, bv, acc0, 0, 0, 0);
        acc1 = __builtin_amdgcn_mfma_f32_16x16x32_bf16(av1, bv, acc1, 0, 0, 0);
    }
    {   // tail step: n in [768,800); x rows end at 784 -> predicate quads 2,3 (A pad is zero)
        const int off = NSTEP * 32 + qo;
        const short8 av0 = *(const short8*)&a0p[off];
        const short8 av1 = *(const short8*)&a1p[off];
        float4 xv0 = make_float4(0.f, 0.f, 0.f, 0.f);
        float4 xv1 = make_float4(0.f, 0.f, 0.f, 0.f);
        if (quad < 2) {
            xv0 = *(const float4*)&xp[off];
            xv1 = *(const float4*)&xp[off + 4];
        }
        const short8 bv = pack8(xv0, xv1);
        acc0 = __builtin_amdgcn_mfma_f32_16x16x32_bf16(av0, bv, acc0, 0, 0, 0);
        acc1 = __builtin_amdgcn_mfma_f32_16x16x32_bf16(av1, bv, acc1, 0, 0, 0);
    }

    __syncthreads();   // wsum_l ready

    // ---- fused epilogue: out = W - wsum*cw ----
    float* ob = out + (size_t)b * KK * CC + c;
    const float* cp = cw + c;
#pragma unroll
    for (int r = 0; r < 4; ++r) {
        const int k0 = quad * 4 + r;
        ob[(size_t)k0 * CC]        = acc0[r] - wsum_l[k0]      * cp[(size_t)k0 * CC];
        ob[(size_t)(k0 + 16) * CC] = acc1[r] - wsum_l[k0 + 16] * cp[(size_t)(k0 + 16) * CC];
    }
}

extern "C" void kernel_launch(void* const* d_in, const int* in_sizes, int n_in,
                              void* d_out, int out_size, void* d_ws, size_t ws_size,
                              hipStream_t stream) {
    const float* x     = (const float*)d_in[0];   // (64, 512, 28, 28)
    const float* cw    = (const float*)d_in[1];   // (32, 512)
    const float* scale = (const float*)d_in[2];   // (32,)
    float* out = (float*)d_out;                   // (64, 32, 512)
    unsigned short* Ag = (unsigned short*)d_ws;

    kPrep<<<dim3(1), dim3(256), 0, stream>>>(cw, Ag);
    kA<<<dim3(NSA, BB), dim3(256), 0, stream>>>(x, scale, Ag);
    kB<<<dim3(8, BB), dim3(256), 0, stream>>>(x, cw, Ag, out);
}

// Round 12
// 181.283 us; speedup vs baseline: 1.0818x; 1.0818x over previous
//
#include <hip/hip_runtime.h>

#define BB 64
#define CC 512
#define NPIX 784
#define KK 32
#define NSA 7           // kA: 7 splits of 128 px (split 6: p0=656, only wave 3 active)
#define AS 800          // A row stride in shorts (784 padded to 25*32)
#define CW_S 520        // cw LDS row stride (shorts): rows 16B-aligned
#define NSTEP 24        // kB full 32-wide n-steps (24*32 = 768), +1 predicated tail

typedef __attribute__((ext_vector_type(8))) short short8;
typedef __attribute__((ext_vector_type(4))) float floatx4;
typedef __attribute__((ext_vector_type(16))) float floatx16;
typedef __attribute__((ext_vector_type(4))) unsigned short ushort4v;

// workspace layout: A bf16 [64][32][800] (3.28 MB), then wsum_p fp32 [7][64][32]
#define WSUM_OFF (BB * KK * AS)   // in shorts; byte offset 3,276,800*2 (16-aligned)

__device__ __forceinline__ unsigned short f2bf(float f) {
    union { float f; unsigned u; } v; v.f = f;
    return (unsigned short)((v.u + 0x7FFFu + ((v.u >> 16) & 1u)) >> 16);
}
__device__ __forceinline__ float bf2f(unsigned short h) {
    union { unsigned u; float f; } v; v.u = ((unsigned)h) << 16; return v.f;
}
__device__ __forceinline__ short8 pack8(const float4& a, const float4& b) {
    short8 r;
    r[0] = (short)f2bf(a.x); r[1] = (short)f2bf(a.y);
    r[2] = (short)f2bf(a.z); r[3] = (short)f2bf(a.w);
    r[4] = (short)f2bf(b.x); r[5] = (short)f2bf(b.y);
    r[6] = (short)f2bf(b.z); r[7] = (short)f2bf(b.w);
    return r;
}

// ---------------------------------------------------------------------------
// kA: per (128-px split, batch): A[k][px] = softmax_k(scale_k*(xsq+csq_k-2 x.c_k))
//  - 32x32x16 MFMA: one 32-px tile per wave -> each x-load instruction spans
//    32 px = 128 B segments (the kB-proven full-line pattern; r3's 16-px waves
//    made 64 B segments = 50% line efficiency = the 2.3 TB/s wall).
//  - a-frag: lane(pl=lane&31, h=lane>>5) holds x[c=kc*16+h*8+j][px=pl] --
//    direct generalization of the verified 16x16 mapping.
//  - same r3 register va/vb double-buffer, zero barriers in main loop.
//  - b-frag: ONE ds_read_b128/step (all 32 k in one frag): cs[pl*CW_S+...].
//  - C/D layout (m74/m101): col=lane&31=k, row=(r&3)+8*(r>>2)+4*h=px.
//    softmax over k = xor-shuffle reduce 1..16 (stays within lane-half).
//  - split 6 (p0=656): waves 0-2 fully duplicate split 5 -> skip compute.
// ---------------------------------------------------------------------------
__global__ __launch_bounds__(256, 4) void kA(const float* __restrict__ x,
                                             const float* __restrict__ cw,
                                             const float* __restrict__ scale,
                                             unsigned short* __restrict__ Ag)
{
    __shared__ __align__(16) unsigned short cs[KK * CW_S];   // 33280 B
    __shared__ float csq_p[8][KK];
    __shared__ float csq_l[KK];
    __shared__ float wredA[4][KK];

    const int t    = threadIdx.x;
    const int lane = t & 63, w = t >> 6;
    const int pl   = lane & 31, h = lane >> 5;
    const int split = blockIdx.x, b = blockIdx.y;
    const int p0    = (split < 6) ? split * 128 : 656;
    const bool active = !(split == 6 && w < 3);   // split 6: only wave 3 has new px

    // ---- zero A pad region n in [784,800) once per batch (idempotent) ----
    if (split == 0 && t < 64) {
        const short8 z = {0, 0, 0, 0, 0, 0, 0, 0};
        const int k = t >> 1, off = (t & 1) * 8;
        *(short8*)&Ag[(size_t)b * KK * AS + (size_t)k * AS + NPIX + off] = z;
    }

    // ---- stage cw -> bf16 LDS ----
#pragma unroll 4
    for (int j = 0; j < 16; ++j) {
        const int qidx = t + j * 256;
        const int row = qidx >> 7, qc = qidx & 127;
        const float4 v = *(const float4*)&cw[row * CC + qc * 4];
        ushort4v p; p.x = f2bf(v.x); p.y = f2bf(v.y); p.z = f2bf(v.z); p.w = f2bf(v.w);
        *(ushort4v*)&cs[row * CW_S + qc * 4] = p;
    }
    __syncthreads();
    // ---- csq ----
    {
        const int k = t & 31, part = t >> 5;
        float s = 0.f;
        for (int i = 0; i < 64; ++i) {
            const float v = bf2f(cs[k * CW_S + part * 64 + i]);
            s += v * v;
        }
        csq_p[part][k] = s;
    }
    __syncthreads();
    if (t < KK) {
        float s = 0.f;
#pragma unroll
        for (int p = 0; p < 8; ++p) s += csq_p[p][t];
        csq_l[t] = s;
    }
    __syncthreads();

    const float sk = scale[pl];      // k = pl
    const float qk = csq_l[pl];

    // ---- main MFMA: wave w owns px-tile [p0 + w*32, +32), contracts all C ----
    const int px = p0 + w * 32 + pl;
    const float* xb = x + (size_t)b * CC * NPIX + px;

    floatx16 acc = {0.f,0.f,0.f,0.f,0.f,0.f,0.f,0.f,0.f,0.f,0.f,0.f,0.f,0.f,0.f,0.f};
    float xsqp = 0.f;

    if (active) {
        float va[8], vb[8];
#pragma unroll
        for (int j = 0; j < 8; ++j) va[j] = xb[(size_t)(h * 8 + j) * NPIX];

#pragma unroll
        for (int kc = 0; kc < 32; kc += 2) {
            // prefetch kc+1 into vb
            {
                const int cb = (kc + 1) * 16 + h * 8;
#pragma unroll
                for (int j = 0; j < 8; ++j) vb[j] = xb[(size_t)(cb + j) * NPIX];
            }
            // process va (kc)
            {
                short8 a;
#pragma unroll
                for (int j = 0; j < 8; ++j) { xsqp += va[j] * va[j]; a[j] = (short)f2bf(va[j]); }
                const short8 bf = *(const short8*)&cs[pl * CW_S + kc * 16 + h * 8];
                acc = __builtin_amdgcn_mfma_f32_32x32x16_bf16(a, bf, acc, 0, 0, 0);
            }
            // prefetch kc+2 into va
            if (kc + 2 < 32) {
                const int cb = (kc + 2) * 16 + h * 8;
#pragma unroll
                for (int j = 0; j < 8; ++j) va[j] = xb[(size_t)(cb + j) * NPIX];
            }
            // process vb (kc+1)
            {
                short8 a;
#pragma unroll
                for (int j = 0; j < 8; ++j) { xsqp += vb[j] * vb[j]; a[j] = (short)f2bf(vb[j]); }
                const short8 bf = *(const short8*)&cs[pl * CW_S + (kc + 1) * 16 + h * 8];
                acc = __builtin_amdgcn_mfma_f32_32x32x16_bf16(a, bf, acc, 0, 0, 0);
            }
        }
    }

    // xsq: lane holds half-sum for px=pl; combine halves
    const float xsqf = xsqp + __shfl_xor(xsqp, 32);

    // fused softmax epilogue; D: col=pl=k, row(px in tile) = (r&3)+8*(r>>2)+4*h
    unsigned short* Ab = Ag + (size_t)b * KK * AS + p0 + w * 32;
    float ts = 0.f;   // per-lane wsum partial for k=pl
    if (active) {
#pragma unroll
        for (int r = 0; r < 16; ++r) {
            const int pwr = (r & 3) + 8 * (r >> 2) + 4 * h;   // px within tile
            const float xq = __shfl(xsqf, pwr);               // lane pwr holds that px's xsq
            const float d = sk * (xq + qk - 2.f * acc[r]);
            float mx = d;
            mx = fmaxf(mx, __shfl_xor(mx, 1));
            mx = fmaxf(mx, __shfl_xor(mx, 2));
            mx = fmaxf(mx, __shfl_xor(mx, 4));
            mx = fmaxf(mx, __shfl_xor(mx, 8));
            mx = fmaxf(mx, __shfl_xor(mx, 16));
            const float e = __expf(d - mx);
            float sm = e;
            sm += __shfl_xor(sm, 1);
            sm += __shfl_xor(sm, 2);
            sm += __shfl_xor(sm, 4);
            sm += __shfl_xor(sm, 8);
            sm += __shfl_xor(sm, 16);
            const float av = e * (1.f / sm);
            Ab[pl * AS + pwr] = f2bf(av);
            // split 6: only px>=768 (rel>=16 in wave 3's tile -> r>=8) are new
            if (split < 6 || r >= 8) ts += av;
        }
    }
    ts += __shfl_xor(ts, 32);
    if (lane < 32) wredA[w][pl] = active ? ts : 0.f;
    __syncthreads();
    if (t < KK) {
        const float s = wredA[0][t] + wredA[1][t] + wredA[2][t] + wredA[3][t];
        float* wsf = (float*)(Ag + WSUM_OFF);
        wsf[(size_t)(split * BB + b) * KK + t] = s;
    }
}

// ---------------------------------------------------------------------------
// kB: per (c-chunk of 64, batch): out[k][c] = sum_n A[k][n] x[c][n] - wsum_k cw[k][c]
//  - barrier-free main loop, A (L2-hot) and x (L3-hot from kA) direct from global
//  - wsum from kA's per-split partials (7 adds per k)
// ---------------------------------------------------------------------------
__global__ __launch_bounds__(256) void kB(const float* __restrict__ x,
                                          const float* __restrict__ cw,
                                          const unsigned short* __restrict__ Ag,
                                          float* __restrict__ out)
{
    __shared__ float wsum_l[KK];

    const int t    = threadIdx.x;
    const int lane = t & 63, w = t >> 6;
    const int col  = lane & 15, quad = lane >> 4;
    const int cch  = blockIdx.x, b = blockIdx.y;

    const unsigned short* Ab = Ag + (size_t)b * KK * AS;

    // ---- wsum: sum kA's 7 per-split partials ----
    if (t < KK) {
        const float* wsf = (const float*)(Ag + WSUM_OFF);
        float s = 0.f;
#pragma unroll
        for (int sp = 0; sp < NSA; ++sp) s += wsf[(size_t)(sp * BB + b) * KK + t];
        wsum_l[t] = s;
    }

    // ---- main GEMM: this wave owns 16 c-rows; contract n = 0..800 ----
    const int c = cch * 64 + w * 16 + col;
    const float* xp = x + ((size_t)b * CC + c) * NPIX;
    const unsigned short* a0p = Ab + (size_t)col * AS;
    const unsigned short* a1p = Ab + (size_t)(col + 16) * AS;
    const int qo = quad * 8;

    floatx4 acc0 = {0.f, 0.f, 0.f, 0.f};
    floatx4 acc1 = {0.f, 0.f, 0.f, 0.f};
#pragma unroll 6
    for (int s = 0; s < NSTEP; ++s) {
        const int off = s * 32 + qo;
        const short8 av0 = *(const short8*)&a0p[off];
        const short8 av1 = *(const short8*)&a1p[off];
        const float4 xv0 = *(const float4*)&xp[off];
        const float4 xv1 = *(const float4*)&xp[off + 4];
        const short8 bv = pack8(xv0, xv1);
        acc0 = __builtin_amdgcn_mfma_f32_16x16x32_bf16(av0, bv, acc0, 0, 0, 0);
        acc1 = __builtin_amdgcn_mfma_f32_16x16x32_bf16(av1, bv, acc1, 0, 0, 0);
    }
    {   // tail step: n in [768,800); x rows end at 784 -> predicate quads 2,3 (A pad is zero)
        const int off = NSTEP * 32 + qo;
        const short8 av0 = *(const short8*)&a0p[off];
        const short8 av1 = *(const short8*)&a1p[off];
        float4 xv0 = make_float4(0.f, 0.f, 0.f, 0.f);
        float4 xv1 = make_float4(0.f, 0.f, 0.f, 0.f);
        if (quad < 2) {
            xv0 = *(const float4*)&xp[off];
            xv1 = *(const float4*)&xp[off + 4];
        }
        const short8 bv = pack8(xv0, xv1);
        acc0 = __builtin_amdgcn_mfma_f32_16x16x32_bf16(av0, bv, acc0, 0, 0, 0);
        acc1 = __builtin_amdgcn_mfma_f32_16x16x32_bf16(av1, bv, acc1, 0, 0, 0);
    }

    __syncthreads();   // wsum_l ready

    // ---- fused epilogue: out = W - wsum*cw ----
    float* ob = out + (size_t)b * KK * CC + c;
    const float* cp = cw + c;
#pragma unroll
    for (int r = 0; r < 4; ++r) {
        const int k0 = quad * 4 + r;
        ob[(size_t)k0 * CC]        = acc0[r] - wsum_l[k0]      * cp[(size_t)k0 * CC];
        ob[(size_t)(k0 + 16) * CC] = acc1[r] - wsum_l[k0 + 16] * cp[(size_t)(k0 + 16) * CC];
    }
}

extern "C" void kernel_launch(void* const* d_in, const int* in_sizes, int n_in,
                              void* d_out, int out_size, void* d_ws, size_t ws_size,
                              hipStream_t stream) {
    const float* x     = (const float*)d_in[0];   // (64, 512, 28, 28)
    const float* cw    = (const float*)d_in[1];   // (32, 512)
    const float* scale = (const float*)d_in[2];   // (32,)
    float* out = (float*)d_out;                   // (64, 32, 512)
    unsigned short* Ag = (unsigned short*)d_ws;   // A bf16 [64][32][800] + wsum_p f32 [7][64][32]

    kA<<<dim3(NSA, BB), dim3(256), 0, stream>>>(x, cw, scale, Ag);
    kB<<<dim3(8, BB), dim3(256), 0, stream>>>(x, cw, Ag, out);
}